// Round 1
// baseline (339.374 us; speedup 1.0000x reference)
//
#include <hip/hip_runtime.h>
#include <hip/hip_bf16.h>

#define D 128
#define NC 5

typedef unsigned int u32;

__device__ __forceinline__ float bf_lo(u32 u) { return __uint_as_float(u << 16); }
__device__ __forceinline__ float bf_hi(u32 u) { return __uint_as_float(u & 0xFFFF0000u); }

// Convert 8 consecutive f32 -> 8 bf16 (RNE), packed as one uint4.
__device__ __forceinline__ void cvt8(const float* __restrict__ src,
                                     __hip_bfloat16* __restrict__ dst, int i) {
    const float4* s = (const float4*)src;
    float4 a = s[i * 2 + 0];
    float4 b = s[i * 2 + 1];
    u32 r[4];
    #pragma unroll
    for (int k = 0; k < 4; ++k) {
        float lo = (k < 2) ? (&a.x)[2 * k]     : (&b.x)[2 * (k - 2)];
        float hi = (k < 2) ? (&a.x)[2 * k + 1] : (&b.x)[2 * (k - 2) + 1];
        u32 l = __hip_bfloat16_raw(__float2bfloat16(lo)).x;
        u32 h = __hip_bfloat16_raw(__float2bfloat16(hi)).x;
        r[k] = l | (h << 16);
    }
    ((uint4*)dst)[i] = make_uint4(r[0], r[1], r[2], r[3]);
}

// ---- Pass 1: convert u_feats, v_feats, W to bf16 in one launch ----
__global__ __launch_bounds__(256) void cvt_all_kernel(
    const float* __restrict__ u_feats, const float* __restrict__ v_feats,
    const float* __restrict__ W,
    __hip_bfloat16* __restrict__ u_bf, __hip_bfloat16* __restrict__ v_bf,
    __hip_bfloat16* __restrict__ W_bf,
    int nu8, int nv8, int nw8)
{
    int i = blockIdx.x * 256 + threadIdx.x;
    if (i < nu8) {
        cvt8(u_feats, u_bf, i);
    } else if (i < nu8 + nv8) {
        cvt8(v_feats, v_bf, i - nu8);
    } else if (i < nu8 + nv8 + nw8) {
        cvt8(W, W_bf, i - nu8 - nv8);
    }
}

// Two edges share one W unpack: per k, unpack 3 bases' bf16 pair once, apply
// to both edges' (u*v) products. ~2x MLP (8 gather loads in flight/lane).
__device__ __forceinline__ void dot8x2(uint4 ua, uint4 va, uint4 ub, uint4 vb,
                                       uint4 w0, uint4 w1, uint4 w2,
                                       float& a0, float& a1, float& a2,
                                       float& b0, float& b1, float& b2) {
    #pragma unroll
    for (int k = 0; k < 4; ++k) {
        u32 ww0 = (&w0.x)[k], ww1 = (&w1.x)[k], ww2 = (&w2.x)[k];
        float w0l = bf_lo(ww0), w0h = bf_hi(ww0);
        float w1l = bf_lo(ww1), w1h = bf_hi(ww1);
        float w2l = bf_lo(ww2), w2h = bf_hi(ww2);
        {
            u32 uu = (&ua.x)[k], vv = (&va.x)[k];
            float pl = bf_lo(uu) * bf_lo(vv);
            float ph = bf_hi(uu) * bf_hi(vv);
            a0 = fmaf(pl, w0l, a0); a0 = fmaf(ph, w0h, a0);
            a1 = fmaf(pl, w1l, a1); a1 = fmaf(ph, w1h, a1);
            a2 = fmaf(pl, w2l, a2); a2 = fmaf(ph, w2h, a2);
        }
        {
            u32 uu = (&ub.x)[k], vv = (&vb.x)[k];
            float pl = bf_lo(uu) * bf_lo(vv);
            float ph = bf_hi(uu) * bf_hi(vv);
            b0 = fmaf(pl, w0l, b0); b0 = fmaf(ph, w0h, b0);
            b1 = fmaf(pl, w1l, b1); b1 = fmaf(ph, w1h, b1);
            b2 = fmaf(pl, w2l, b2); b2 = fmaf(ph, w2h, b2);
        }
    }
}

// ---- Pass 2: 8 lanes/edge, 2 edges per 8-lane group (64 edges/block) ----
__global__ __launch_bounds__(256) void bilinear_bf16x2_kernel(
    const __hip_bfloat16* __restrict__ u_bf,   // [NUM_USERS,128] bf16 (ws)
    const __hip_bfloat16* __restrict__ v_bf,   // [NUM_ITEMS,128] bf16 (ws)
    const __hip_bfloat16* __restrict__ W_bf,   // [3,128] bf16 (ws)
    const int*   __restrict__ u_idx,
    const int*   __restrict__ v_idx,
    const float* __restrict__ scalars,         // [3,5] f32
    const float* __restrict__ u_bias,          // [*,5] f32
    const float* __restrict__ v_bias,          // [*,5] f32
    float* __restrict__ out,                   // [E,5] f32
    int E)
{
    const int lane = threadIdx.x & 7;    // 8 lanes/edge: 16 bf16 (32B) each
    const int grp  = threadIdx.x >> 3;   // 0..31
    const int base = blockIdx.x * 64;
    const int e0   = base + grp;
    if (e0 >= E) return;
    const int e1r  = base + 32 + grp;
    const bool has1 = (e1r < E);
    const int e1   = has1 ? e1r : e0;    // clamp: duplicate work, store guarded

    const int ui0 = __builtin_nontemporal_load(u_idx + e0);
    const int vi0 = __builtin_nontemporal_load(v_idx + e0);
    const int ui1 = __builtin_nontemporal_load(u_idx + e1);
    const int vi1 = __builtin_nontemporal_load(v_idx + e1);

    // 8 independent row-gather loads in flight per lane.
    const uint4* ur0 = (const uint4*)(u_bf + (size_t)ui0 * D);
    const uint4* vr0 = (const uint4*)(v_bf + (size_t)vi0 * D);
    const uint4* ur1 = (const uint4*)(u_bf + (size_t)ui1 * D);
    const uint4* vr1 = (const uint4*)(v_bf + (size_t)vi1 * D);
    uint4 ua0 = ur0[lane * 2 + 0];
    uint4 ua1 = ur0[lane * 2 + 1];
    uint4 va0 = vr0[lane * 2 + 0];
    uint4 va1 = vr0[lane * 2 + 1];
    uint4 ub0 = ur1[lane * 2 + 0];
    uint4 ub1 = ur1[lane * 2 + 1];
    uint4 vb0 = vr1[lane * 2 + 0];
    uint4 vb1 = vr1[lane * 2 + 1];

    // Hoisted cached loads (overlap the gathers).
    const uint4* Wr = (const uint4*)W_bf;                      // 16 uint4/basis
    uint4 w00 = Wr[ 0 + lane * 2], w01 = Wr[ 1 + lane * 2];
    uint4 w10 = Wr[16 + lane * 2], w11 = Wr[17 + lane * 2];
    uint4 w20 = Wr[32 + lane * 2], w21 = Wr[33 + lane * 2];

    float bs0 = 0.f, bs1 = 0.f, sc0 = 0.f, sc1 = 0.f, sc2 = 0.f;
    if (lane < NC) {
        bs0 = u_bias[(size_t)ui0 * NC + lane] + v_bias[(size_t)vi0 * NC + lane];
        bs1 = u_bias[(size_t)ui1 * NC + lane] + v_bias[(size_t)vi1 * NC + lane];
        sc0 = scalars[0 * NC + lane];
        sc1 = scalars[1 * NC + lane];
        sc2 = scalars[2 * NC + lane];
    }

    float a0 = 0.f, a1 = 0.f, a2 = 0.f;
    float b0 = 0.f, b1 = 0.f, b2 = 0.f;
    dot8x2(ua0, va0, ub0, vb0, w00, w10, w20, a0, a1, a2, b0, b1, b2);
    dot8x2(ua1, va1, ub1, vb1, w01, w11, w21, a0, a1, a2, b0, b1, b2);

    // Reduce across the 8-lane group (3 steps, 6 accumulators).
    #pragma unroll
    for (int off = 4; off > 0; off >>= 1) {
        a0 += __shfl_xor(a0, off, 8);
        a1 += __shfl_xor(a1, off, 8);
        a2 += __shfl_xor(a2, off, 8);
        b0 += __shfl_xor(b0, off, 8);
        b1 += __shfl_xor(b1, off, 8);
        b2 += __shfl_xor(b2, off, 8);
    }

    if (lane < NC) {
        float r0 = a0 * sc0 + a1 * sc1 + a2 * sc2 + bs0;
        __builtin_nontemporal_store(r0, out + (size_t)e0 * NC + lane);
        if (has1) {
            float r1 = b0 * sc0 + b1 * sc1 + b2 * sc2 + bs1;
            __builtin_nontemporal_store(r1, out + (size_t)e1 * NC + lane);
        }
    }
}

// ---- Fallback (f32 gathers) if ws too small ----
__global__ __launch_bounds__(256) void bilinear_f32_kernel(
    const float* __restrict__ u_feats, const float* __restrict__ v_feats,
    const int* __restrict__ u_idx, const int* __restrict__ v_idx,
    const float* __restrict__ W, const float* __restrict__ scalars,
    const float* __restrict__ u_bias, const float* __restrict__ v_bias,
    float* __restrict__ out, int E)
{
    const int lane = threadIdx.x & 15;
    const int grp  = threadIdx.x >> 4;
    const int e    = blockIdx.x * 16 + grp;
    if (e >= E) return;
    const int ui = u_idx[e];
    const int vi = v_idx[e];
    const float4* ur = (const float4*)(u_feats + (size_t)ui * D);
    const float4* vr = (const float4*)(v_feats + (size_t)vi * D);
    const float4* Wr = (const float4*)W;
    float4 ua0 = ur[lane*2+0], ua1 = ur[lane*2+1];
    float4 va0 = vr[lane*2+0], va1 = vr[lane*2+1];
    float4 w00 = Wr[ 0+lane*2], w01 = Wr[ 1+lane*2];
    float4 w10 = Wr[32+lane*2], w11 = Wr[33+lane*2];
    float4 w20 = Wr[64+lane*2], w21 = Wr[65+lane*2];
    float s0=0.f, s1=0.f, s2=0.f;
    #pragma unroll
    for (int k = 0; k < 4; ++k) {
        float p = (&ua0.x)[k] * (&va0.x)[k];
        s0 = fmaf(p, (&w00.x)[k], s0);
        s1 = fmaf(p, (&w10.x)[k], s1);
        s2 = fmaf(p, (&w20.x)[k], s2);
    }
    #pragma unroll
    for (int k = 0; k < 4; ++k) {
        float p = (&ua1.x)[k] * (&va1.x)[k];
        s0 = fmaf(p, (&w01.x)[k], s0);
        s1 = fmaf(p, (&w11.x)[k], s1);
        s2 = fmaf(p, (&w21.x)[k], s2);
    }
    #pragma unroll
    for (int off = 8; off > 0; off >>= 1) {
        s0 += __shfl_xor(s0, off, 16);
        s1 += __shfl_xor(s1, off, 16);
        s2 += __shfl_xor(s2, off, 16);
    }
    if (lane < NC) {
        float r = s0*scalars[0*NC+lane] + s1*scalars[1*NC+lane] + s2*scalars[2*NC+lane]
                + u_bias[(size_t)ui*NC+lane] + v_bias[(size_t)vi*NC+lane];
        out[(size_t)e*NC+lane] = r;
    }
}

extern "C" void kernel_launch(void* const* d_in, const int* in_sizes, int n_in,
                              void* d_out, int out_size, void* d_ws, size_t ws_size,
                              hipStream_t stream) {
    const float* u_feats = (const float*)d_in[0];
    const float* v_feats = (const float*)d_in[1];
    const int*   u_idx   = (const int*)d_in[2];
    const int*   v_idx   = (const int*)d_in[3];
    const float* W       = (const float*)d_in[4];
    const float* scalars = (const float*)d_in[5];
    const float* u_bias  = (const float*)d_in[6];
    const float* v_bias  = (const float*)d_in[7];
    float* out           = (float*)d_out;

    const int nu = in_sizes[0];   // NUM_USERS * 128
    const int nv = in_sizes[1];   // NUM_ITEMS * 128
    const int nw = in_sizes[4];   // 3 * 128
    const int E  = in_sizes[2];

    const size_t need = (size_t)(nu + nv + nw) * sizeof(__hip_bfloat16);
    if (ws_size >= need) {
        __hip_bfloat16* u_bf = (__hip_bfloat16*)d_ws;
        __hip_bfloat16* v_bf = u_bf + nu;
        __hip_bfloat16* W_bf = v_bf + nv;
        const int nu8 = nu / 8, nv8 = nv / 8, nw8 = nw / 8;
        const int tot = nu8 + nv8 + nw8;
        cvt_all_kernel<<<(tot + 255) / 256, 256, 0, stream>>>(
            u_feats, v_feats, W, u_bf, v_bf, W_bf, nu8, nv8, nw8);
        bilinear_bf16x2_kernel<<<(E + 63) / 64, 256, 0, stream>>>(
            u_bf, v_bf, W_bf, u_idx, v_idx, scalars, u_bias, v_bias, out, E);
    } else {
        bilinear_f32_kernel<<<(E + 15) / 16, 256, 0, stream>>>(
            u_feats, v_feats, u_idx, v_idx, W, scalars, u_bias, v_bias, out, E);
    }
}

// Round 3
// 338.735 us; speedup vs baseline: 1.0019x; 1.0019x over previous
//
#include <hip/hip_runtime.h>
#include <hip/hip_bf16.h>

#define D 128
#define NC 5

typedef unsigned int u32;
typedef float f32x4 __attribute__((ext_vector_type(4)));   // clang vector: valid for NT builtins

__device__ __forceinline__ float bf_lo(u32 u) { return __uint_as_float(u << 16); }
__device__ __forceinline__ float bf_hi(u32 u) { return __uint_as_float(u & 0xFFFF0000u); }

// Convert 8 consecutive f32 -> 8 bf16 (RNE), packed as one uint4.
// NT loads: sources are streamed once, don't pollute L2/L3 ahead of the
// gather-heavy bilinear pass.
__device__ __forceinline__ void cvt8(const float* __restrict__ src,
                                     __hip_bfloat16* __restrict__ dst, int i) {
    const f32x4* s = (const f32x4*)src;
    f32x4 a = __builtin_nontemporal_load(&s[i * 2 + 0]);
    f32x4 b = __builtin_nontemporal_load(&s[i * 2 + 1]);
    u32 r[4];
    #pragma unroll
    for (int k = 0; k < 4; ++k) {
        float lo = (k < 2) ? a[2 * k]     : b[2 * (k - 2)];
        float hi = (k < 2) ? a[2 * k + 1] : b[2 * (k - 2) + 1];
        u32 l = __hip_bfloat16_raw(__float2bfloat16(lo)).x;
        u32 h = __hip_bfloat16_raw(__float2bfloat16(hi)).x;
        r[k] = l | (h << 16);
    }
    // Plain store: bf16 tables are re-read ~20x by the bilinear pass.
    ((uint4*)dst)[i] = make_uint4(r[0], r[1], r[2], r[3]);
}

// ---- Pass 1: convert u_feats, v_feats, W to bf16 (grid-stride) ----
__global__ __launch_bounds__(256) void cvt_all_kernel(
    const float* __restrict__ u_feats, const float* __restrict__ v_feats,
    const float* __restrict__ W,
    __hip_bfloat16* __restrict__ u_bf, __hip_bfloat16* __restrict__ v_bf,
    __hip_bfloat16* __restrict__ W_bf,
    int nu8, int nv8, int nw8)
{
    const int tot = nu8 + nv8 + nw8;
    const int stride = gridDim.x * 256;
    for (int i = blockIdx.x * 256 + threadIdx.x; i < tot; i += stride) {
        if (i < nu8) {
            cvt8(u_feats, u_bf, i);
        } else if (i < nu8 + nv8) {
            cvt8(v_feats, v_bf, i - nu8);
        } else {
            cvt8(W, W_bf, i - nu8 - nv8);
        }
    }
}

__device__ __forceinline__ void dot8(uint4 u, uint4 v, uint4 w0, uint4 w1, uint4 w2,
                                     float& s0, float& s1, float& s2) {
    #pragma unroll
    for (int k = 0; k < 4; ++k) {
        u32 uu = (&u.x)[k], vv = (&v.x)[k];
        u32 a0 = (&w0.x)[k], a1 = (&w1.x)[k], a2 = (&w2.x)[k];
        float plo = bf_lo(uu) * bf_lo(vv);
        float phi = bf_hi(uu) * bf_hi(vv);
        s0 = fmaf(plo, bf_lo(a0), s0); s0 = fmaf(phi, bf_hi(a0), s0);
        s1 = fmaf(plo, bf_lo(a1), s1); s1 = fmaf(phi, bf_hi(a1), s1);
        s2 = fmaf(plo, bf_lo(a2), s2); s2 = fmaf(phi, bf_hi(a2), s2);
    }
}

// ---- Pass 2: 8 lanes/edge, 16 bf16 per lane per row (2 uint4 gathers/row) ----
// x1 form: best measured (187us, occupancy 58%). The gather/L2-miss path is
// throughput-saturated at ~3.85 TB/s; keep max wave concurrency feeding it.
__global__ __launch_bounds__(256) void bilinear_bf16_kernel(
    const __hip_bfloat16* __restrict__ u_bf,   // [NUM_USERS,128] bf16 (ws)
    const __hip_bfloat16* __restrict__ v_bf,   // [NUM_ITEMS,128] bf16 (ws)
    const __hip_bfloat16* __restrict__ W_bf,   // [3,128] bf16 (ws)
    const int*   __restrict__ u_idx,
    const int*   __restrict__ v_idx,
    const float* __restrict__ scalars,         // [3,5] f32
    const float* __restrict__ u_bias,          // [*,5] f32
    const float* __restrict__ v_bias,          // [*,5] f32
    float* __restrict__ out,                   // [E,5] f32
    int E)
{
    const int lane = threadIdx.x & 7;    // 8 lanes/edge: 16 bf16 (32B) each
    const int grp  = threadIdx.x >> 3;   // 32 edges per 256-thread block
    const int e    = blockIdx.x * 32 + grp;
    if (e >= E) return;

    const int ui = __builtin_nontemporal_load(u_idx + e);
    const int vi = __builtin_nontemporal_load(v_idx + e);

    // 4 independent row-gather loads in flight per lane.
    const uint4* ur = (const uint4*)(u_bf + (size_t)ui * D);   // 16 uint4/row
    const uint4* vr = (const uint4*)(v_bf + (size_t)vi * D);
    uint4 ua0 = ur[lane * 2 + 0];
    uint4 ua1 = ur[lane * 2 + 1];
    uint4 va0 = vr[lane * 2 + 0];
    uint4 va1 = vr[lane * 2 + 1];

    // Bias gathers issued early so they overlap the row gathers.
    float bsum = 0.f, sc0 = 0.f, sc1 = 0.f, sc2 = 0.f;
    if (lane < NC) {
        bsum = u_bias[(size_t)ui * NC + lane] + v_bias[(size_t)vi * NC + lane];
        sc0 = scalars[0 * NC + lane];
        sc1 = scalars[1 * NC + lane];
        sc2 = scalars[2 * NC + lane];
    }

    // Hoisted cached loads (L1/L2-hot, 768B table).
    const uint4* Wr = (const uint4*)W_bf;                      // 16 uint4/basis
    uint4 w00 = Wr[ 0 + lane * 2], w01 = Wr[ 1 + lane * 2];
    uint4 w10 = Wr[16 + lane * 2], w11 = Wr[17 + lane * 2];
    uint4 w20 = Wr[32 + lane * 2], w21 = Wr[33 + lane * 2];

    float s0 = 0.f, s1 = 0.f, s2 = 0.f;
    dot8(ua0, va0, w00, w10, w20, s0, s1, s2);
    dot8(ua1, va1, w01, w11, w21, s0, s1, s2);

    // Reduce across the 8-lane group (3 steps).
    #pragma unroll
    for (int off = 4; off > 0; off >>= 1) {
        s0 += __shfl_xor(s0, off, 8);
        s1 += __shfl_xor(s1, off, 8);
        s2 += __shfl_xor(s2, off, 8);
    }

    if (lane < NC) {
        float r = s0 * sc0 + s1 * sc1 + s2 * sc2 + bsum;
        __builtin_nontemporal_store(r, out + (size_t)e * NC + lane);
    }
}

// ---- Fallback (f32 gathers) if ws too small ----
__global__ __launch_bounds__(256) void bilinear_f32_kernel(
    const float* __restrict__ u_feats, const float* __restrict__ v_feats,
    const int* __restrict__ u_idx, const int* __restrict__ v_idx,
    const float* __restrict__ W, const float* __restrict__ scalars,
    const float* __restrict__ u_bias, const float* __restrict__ v_bias,
    float* __restrict__ out, int E)
{
    const int lane = threadIdx.x & 15;
    const int grp  = threadIdx.x >> 4;
    const int e    = blockIdx.x * 16 + grp;
    if (e >= E) return;
    const int ui = u_idx[e];
    const int vi = v_idx[e];
    const float4* ur = (const float4*)(u_feats + (size_t)ui * D);
    const float4* vr = (const float4*)(v_feats + (size_t)vi * D);
    const float4* Wr = (const float4*)W;
    float4 ua0 = ur[lane*2+0], ua1 = ur[lane*2+1];
    float4 va0 = vr[lane*2+0], va1 = vr[lane*2+1];
    float4 w00 = Wr[ 0+lane*2], w01 = Wr[ 1+lane*2];
    float4 w10 = Wr[32+lane*2], w11 = Wr[33+lane*2];
    float4 w20 = Wr[64+lane*2], w21 = Wr[65+lane*2];
    float s0=0.f, s1=0.f, s2=0.f;
    #pragma unroll
    for (int k = 0; k < 4; ++k) {
        float p = (&ua0.x)[k] * (&va0.x)[k];
        s0 = fmaf(p, (&w00.x)[k], s0);
        s1 = fmaf(p, (&w10.x)[k], s1);
        s2 = fmaf(p, (&w20.x)[k], s2);
    }
    #pragma unroll
    for (int k = 0; k < 4; ++k) {
        float p = (&ua1.x)[k] * (&va1.x)[k];
        s0 = fmaf(p, (&w01.x)[k], s0);
        s1 = fmaf(p, (&w11.x)[k], s1);
        s2 = fmaf(p, (&w21.x)[k], s2);
    }
    #pragma unroll
    for (int off = 8; off > 0; off >>= 1) {
        s0 += __shfl_xor(s0, off, 16);
        s1 += __shfl_xor(s1, off, 16);
        s2 += __shfl_xor(s2, off, 16);
    }
    if (lane < NC) {
        float r = s0*scalars[0*NC+lane] + s1*scalars[1*NC+lane] + s2*scalars[2*NC+lane]
                + u_bias[(size_t)ui*NC+lane] + v_bias[(size_t)vi*NC+lane];
        out[(size_t)e*NC+lane] = r;
    }
}

extern "C" void kernel_launch(void* const* d_in, const int* in_sizes, int n_in,
                              void* d_out, int out_size, void* d_ws, size_t ws_size,
                              hipStream_t stream) {
    const float* u_feats = (const float*)d_in[0];
    const float* v_feats = (const float*)d_in[1];
    const int*   u_idx   = (const int*)d_in[2];
    const int*   v_idx   = (const int*)d_in[3];
    const float* W       = (const float*)d_in[4];
    const float* scalars = (const float*)d_in[5];
    const float* u_bias  = (const float*)d_in[6];
    const float* v_bias  = (const float*)d_in[7];
    float* out           = (float*)d_out;

    const int nu = in_sizes[0];   // NUM_USERS * 128
    const int nv = in_sizes[1];   // NUM_ITEMS * 128
    const int nw = in_sizes[4];   // 3 * 128
    const int E  = in_sizes[2];

    const size_t need = (size_t)(nu + nv + nw) * sizeof(__hip_bfloat16);
    if (ws_size >= need) {
        __hip_bfloat16* u_bf = (__hip_bfloat16*)d_ws;
        __hip_bfloat16* v_bf = u_bf + nu;
        __hip_bfloat16* W_bf = v_bf + nv;
        const int nu8 = nu / 8, nv8 = nv / 8, nw8 = nw / 8;
        const int tot = nu8 + nv8 + nw8;
        int cvt_blocks = (tot + 255) / 256;
        if (cvt_blocks > 2048) cvt_blocks = 2048;   // grid-stride cap
        cvt_all_kernel<<<cvt_blocks, 256, 0, stream>>>(
            u_feats, v_feats, W, u_bf, v_bf, W_bf, nu8, nv8, nw8);
        bilinear_bf16_kernel<<<(E + 31) / 32, 256, 0, stream>>>(
            u_bf, v_bf, W_bf, u_idx, v_idx, scalars, u_bias, v_bias, out, E);
    } else {
        bilinear_f32_kernel<<<(E + 15) / 16, 256, 0, stream>>>(
            u_feats, v_feats, u_idx, v_idx, W, scalars, u_bias, v_bias, out, E);
    }
}